// Round 1
// 612.459 us; speedup vs baseline: 1.1558x; 1.1558x over previous
//
#include <hip/hip_runtime.h>
#include <hip/hip_fp16.h>
#include <math.h>

#define TT 8192
#define LOG2T 13
#define CC 64
#define BB 64
#define NTHREADS 256
#define TWO_PI 6.28318530717958647692f

// ============================================================================
// Four-step FFT: 8192 = N1(64) * N2(128).  t = n1 + 64*n2, k = 128*k1 + k2.
// All kernels are now LDS-free / barrier-free:
//  - kA/kC: each thread-quartet-group q owns a 32-element output block of the
//    128-pt FFT. The two cross-block stages are fused into one radix-4 combine
//    computed straight from global (4 waves of a block re-read the same 32 KiB
//    -> L1/L2 absorb it). The remaining 5 stages run in registers with
//    compile-time indices.
//  - kB: the full 64-pt fwd FFT -> phase pointwise -> 64-pt inv FFT lives in
//    one thread's registers (64 x float2).
// ws  (kernel A out, aliased onto d_out): [b][k2][n1][c]   (half2)
// ws2 (kernel B out, in d_ws):            [b][n1][k2][c]   (half2)
// Mask handling: masked-out channels skip phase replacement in B, so the
// round-trip FFT->IFFT reproduces the input.
// ============================================================================

__device__ __forceinline__ float2 cmulf(float2 a, float co, float si) {
  return make_float2(a.x * co - a.y * si, a.x * si + a.y * co);
}

// ---- Kernel A: per (b, n1): 64 channels x 128-pt forward FFT, reg-resident --
__global__ __launch_bounds__(NTHREADS) void kA(const float* __restrict__ wav,
                                               __half2* __restrict__ ws) {
  const int b = blockIdx.x >> 6, n1 = blockIdx.x & 63;
  const int tid = threadIdx.x, c = tid & 63, q = tid >> 6;  // q wave-uniform
  const float* wp = wav + ((size_t)b * TT + n1) * CC + c;

  // output block q twiddle: W128^{-sq*j}; sq = {0,2,1,3} for q = {0,1,2,3}
  const int sqi = (q == 0) ? 0 : (q == 1) ? 2 : (q == 2) ? 1 : 3;
  const float angC = -(TWO_PI / 128.0f) * (float)sqi;

  // Radix-4 first step (stages hlf=64,32 fused) directly from global.
  float2 X[32];
  #pragma unroll
  for (int j = 0; j < 32; ++j) {
    const float a  = wp[(size_t)(j      ) * (64 * CC)];
    const float bb = wp[(size_t)(j + 32) * (64 * CC)];
    const float cc = wp[(size_t)(j + 64) * (64 * CC)];
    const float dd = wp[(size_t)(j + 96) * (64 * CC)];
    float2 base;
    if (q == 0)      base = make_float2((a + cc) + (bb + dd), 0.0f);
    else if (q == 1) base = make_float2((a + cc) - (bb + dd), 0.0f);
    else if (q == 2) base = make_float2(a - cc, dd - bb);   // (a-c) - i(b-d)
    else             base = make_float2(a - cc, bb - dd);   // (a-c) + i(b-d)
    if (j == 0) { X[0] = base; }
    else {
      float s, co;
      __sincosf(angC * (float)j, &s, &co);
      X[j] = cmulf(base, co, s);
    }
  }

  // 5 register-resident DIF stages over the 32-block (W = e^{-i...}).
  #pragma unroll
  for (int hlf = 16; hlf >= 1; hlf >>= 1) {
    #pragma unroll
    for (int m = 0; m < 16; ++m) {
      const int j = m & (hlf - 1);
      const int i1 = ((m & ~(hlf - 1)) << 1) | j;
      const int i2 = i1 + hlf;
      const float2 u = X[i1], v = X[i2];
      const float dx = u.x - v.x, dy = u.y - v.y;
      X[i1] = make_float2(u.x + v.x, u.y + v.y);
      if (j == 0) {
        X[i2] = make_float2(dx, dy);
      } else {
        float s, co;
        __sincosf(-(float)M_PI / (float)hlf * (float)j, &s, &co);
        X[i2] = make_float2(dx * co - dy * s, dx * s + dy * co);
      }
    }
  }

  // Twiddle by W8192^{-n1*k2} and store ws[b][k2][n1][c]; k2 = br7(32q+m).
  const size_t wbase = (size_t)b * (128 * 4096) + (size_t)n1 * 64 + c;
  #pragma unroll
  for (int m = 0; m < 32; ++m) {
    const int p = (q << 5) | m;
    const int k2 = __brev((unsigned)p) >> 25;
    float s, co;
    __sincosf(-(TWO_PI / 8192.0f) * (float)(n1 * k2), &s, &co);
    const float2 v = cmulf(X[m], co, s);
    ws[wbase + (size_t)k2 * 4096] = __floats2half2_rn(v.x, v.y);
  }
}

// ---- Kernel B: per (b, k2, c): full 64-pt fwd FFT, phase replace, inv FFT --
// One thread = one channel's entire 64-pt transform pair, all in registers.
__global__ __launch_bounds__(NTHREADS) void kB(const __half2* __restrict__ ws,
                                               const float* __restrict__ ph,
                                               const float* __restrict__ mask,
                                               __half2* __restrict__ ws2) {
  const int b = blockIdx.x >> 5;
  const int k2 = ((blockIdx.x & 31) << 2) | (threadIdx.x >> 6);  // wave-uniform
  const int c = threadIdx.x & 63;

  const __half2* rp = ws + ((size_t)(b * 128 + k2) * 64) * 64 + c;
  float2 X[64];
  #pragma unroll
  for (int n1 = 0; n1 < 64; ++n1) X[n1] = __half22float2(rp[(size_t)n1 * 64]);

  // forward 64-pt DIF (natural in -> bitrev out), W = e^{-i...}
  #pragma unroll
  for (int hlf = 32; hlf >= 1; hlf >>= 1) {
    #pragma unroll
    for (int m = 0; m < 32; ++m) {
      const int j = m & (hlf - 1);
      const int i1 = ((m & ~(hlf - 1)) << 1) | j;
      const int i2 = i1 + hlf;
      const float2 u = X[i1], v = X[i2];
      const float dx = u.x - v.x, dy = u.y - v.y;
      X[i1] = make_float2(u.x + v.x, u.y + v.y);
      if (j == 0) {
        X[i2] = make_float2(dx, dy);
      } else {
        float s, co;
        __sincosf(-(float)M_PI / (float)hlf * (float)j, &s, &co);
        X[i2] = make_float2(dx * co - dy * s, dx * s + dy * co);
      }
    }
  }

  // Pointwise: position p holds k1 = br6(p); full freq k = 128*k1 + k2.
  const float msk = mask[(b << 6) + c];
  if (msk < 0.5f) {
    const size_t pbase = ((size_t)b * TT + k2) * CC + c;
    #pragma unroll
    for (int p = 0; p < 64; ++p) {
      const int k1 = __brev((unsigned)p) >> 26;
      const float phi = ph[pbase + ((size_t)k1 << 13)];
      const float2 v = X[p];
      const float amp = sqrtf(v.x * v.x + v.y * v.y);
      float s, co;
      __sincosf(TWO_PI * phi, &s, &co);
      X[p] = make_float2(amp * co, amp * s);
    }
  }

  // inverse 64-pt DIT (bitrev in -> natural out), W = e^{+i...}
  #pragma unroll
  for (int hlf = 1; hlf <= 32; hlf <<= 1) {
    #pragma unroll
    for (int m = 0; m < 32; ++m) {
      const int j = m & (hlf - 1);
      const int i1 = ((m & ~(hlf - 1)) << 1) | j;
      const int i2 = i1 + hlf;
      const float2 u = X[i1], w = X[i2];
      float tr, ti;
      if (j == 0) { tr = w.x; ti = w.y; }
      else {
        float s, co;
        __sincosf((float)M_PI / (float)hlf * (float)j, &s, &co);
        tr = w.x * co - w.y * s; ti = w.x * s + w.y * co;
      }
      X[i1] = make_float2(u.x + tr, u.y + ti);
      X[i2] = make_float2(u.x - tr, u.y - ti);
    }
  }

  // Inverse outer twiddle W8192^{+n1*k2}, store ws2[b][n1][k2][c]
  #pragma unroll
  for (int n1 = 0; n1 < 64; ++n1) {
    float s, co;
    __sincosf((TWO_PI / 8192.0f) * (float)(n1 * k2), &s, &co);
    const float2 v = cmulf(X[n1], co, s);
    ws2[(((size_t)b * 64 + n1) * 128 + k2) * 64 + c] = __floats2half2_rn(v.x, v.y);
  }
}

// ---- Kernel C: per (b, n1): 64 channels x 128-pt inverse FFT, reg-resident --
__global__ __launch_bounds__(NTHREADS) void kC(const __half2* __restrict__ ws2,
                                               float* __restrict__ out) {
  const int b = blockIdx.x >> 6, n1 = blockIdx.x & 63;
  const int tid = threadIdx.x, c = tid & 63, q = tid >> 6;
  const __half2* rp = ws2 + (size_t)blockIdx.x * 8192 + c;  // [k2][c]

  const int sqi = (q == 0) ? 0 : (q == 1) ? 2 : (q == 2) ? 1 : 3;
  const float angC = (TWO_PI / 128.0f) * (float)sqi;

  // Radix-4 first step (stages hlf=64,32 fused) from global, W = e^{+i...}
  float2 X[32];
  #pragma unroll
  for (int j = 0; j < 32; ++j) {
    const float2 a  = __half22float2(rp[(size_t)(j      ) * 64]);
    const float2 bb = __half22float2(rp[(size_t)(j + 32) * 64]);
    const float2 cc = __half22float2(rp[(size_t)(j + 64) * 64]);
    const float2 dd = __half22float2(rp[(size_t)(j + 96) * 64]);
    float2 base;
    if (q == 0)
      base = make_float2((a.x + cc.x) + (bb.x + dd.x), (a.y + cc.y) + (bb.y + dd.y));
    else if (q == 1)
      base = make_float2((a.x + cc.x) - (bb.x + dd.x), (a.y + cc.y) - (bb.y + dd.y));
    else if (q == 2)  // (a-c) + i(b-d)
      base = make_float2((a.x - cc.x) - (bb.y - dd.y), (a.y - cc.y) + (bb.x - dd.x));
    else              // (a-c) - i(b-d)
      base = make_float2((a.x - cc.x) + (bb.y - dd.y), (a.y - cc.y) - (bb.x - dd.x));
    if (j == 0) { X[0] = base; }
    else {
      float s, co;
      __sincosf(angC * (float)j, &s, &co);
      X[j] = cmulf(base, co, s);
    }
  }

  // 5 register-resident DIF stages, W = e^{+i...}
  #pragma unroll
  for (int hlf = 16; hlf >= 1; hlf >>= 1) {
    #pragma unroll
    for (int m = 0; m < 16; ++m) {
      const int j = m & (hlf - 1);
      const int i1 = ((m & ~(hlf - 1)) << 1) | j;
      const int i2 = i1 + hlf;
      const float2 u = X[i1], v = X[i2];
      const float dx = u.x - v.x, dy = u.y - v.y;
      X[i1] = make_float2(u.x + v.x, u.y + v.y);
      if (j == 0) {
        X[i2] = make_float2(dx, dy);
      } else {
        float s, co;
        __sincosf((float)M_PI / (float)hlf * (float)j, &s, &co);
        X[i2] = make_float2(dx * co - dy * s, dx * s + dy * co);
      }
    }
  }

  // Position p holds n2 = br7(p): out[b][n1 + 64*n2][c] = Re * (1/8192)
  const size_t obase = (size_t)b * (TT * CC) + (size_t)n1 * CC + c;
  #pragma unroll
  for (int m = 0; m < 32; ++m) {
    const int p = (q << 5) | m;
    const int n2 = __brev((unsigned)p) >> 25;
    out[obase + ((size_t)n2 << 6) * CC] = X[m].x * (1.0f / 8192.0f);
  }
}

// ---- Fallback (R1 single-kernel, correct but slow) if ws is too small ----
__global__ __launch_bounds__(NTHREADS) void ft_surrogate_fallback(
    const float* __restrict__ wav, const float* __restrict__ ph,
    const float* __restrict__ mask, float* __restrict__ out) {
  const int bc = blockIdx.x;
  const int c = bc & (CC - 1);
  const int b = bc >> 6;
  const int tid = threadIdx.x;
  const size_t base = (size_t)b * TT * CC + (size_t)c;
  const float m = mask[bc];
  if (!(m < 0.5f)) {
    for (int t = tid; t < TT; t += NTHREADS)
      out[base + (size_t)t * CC] = wav[base + (size_t)t * CC];
    return;
  }
  __shared__ float2 X[TT];
  for (int t = tid; t < TT; t += NTHREADS)
    X[t] = make_float2(wav[base + (size_t)t * CC], 0.0f);
  __syncthreads();
  for (int len = TT, hlf = TT >> 1; len >= 2; len >>= 1, hlf >>= 1) {
    const float ang_scale = -TWO_PI / (float)len;
    for (int it = 0; it < (TT / 2) / NTHREADS; ++it) {
      const int m2 = tid + it * NTHREADS;
      const int j = m2 & (hlf - 1);
      const int i1 = ((m2 & ~(hlf - 1)) << 1) | j;
      const int i2 = i1 + hlf;
      float2 u = X[i1], v = X[i2];
      float ar = u.x + v.x, ai = u.y + v.y;
      float br = u.x - v.x, bi = u.y - v.y;
      float s, cth;
      __sincosf(ang_scale * (float)j, &s, &cth);
      X[i1] = make_float2(ar, ai);
      X[i2] = make_float2(br * cth - bi * s, br * s + bi * cth);
    }
    __syncthreads();
  }
  for (int p = tid; p < TT; p += NTHREADS) {
    const int k = (int)(__brev((unsigned)p) >> (32 - LOG2T));
    float2 v = X[p];
    float amp = sqrtf(v.x * v.x + v.y * v.y);
    float phi = ph[(size_t)b * TT * CC + (size_t)k * CC + (size_t)c];
    float s, cth;
    __sincosf(TWO_PI * phi, &s, &cth);
    X[p] = make_float2(amp * cth, amp * s);
  }
  __syncthreads();
  for (int len = 2, hlf = 1; len <= TT; len <<= 1, hlf <<= 1) {
    const float ang_scale = TWO_PI / (float)len;
    for (int it = 0; it < (TT / 2) / NTHREADS; ++it) {
      const int m2 = tid + it * NTHREADS;
      const int j = m2 & (hlf - 1);
      const int i1 = ((m2 & ~(hlf - 1)) << 1) | j;
      const int i2 = i1 + hlf;
      float s, cth;
      __sincosf(ang_scale * (float)j, &s, &cth);
      float2 u = X[i1], w = X[i2];
      float vr = w.x * cth - w.y * s;
      float vi = w.x * s + w.y * cth;
      X[i1] = make_float2(u.x + vr, u.y + vi);
      X[i2] = make_float2(u.x - vr, u.y - vi);
    }
    __syncthreads();
  }
  const float invN = 1.0f / (float)TT;
  for (int t = tid; t < TT; t += NTHREADS)
    out[base + (size_t)t * CC] = X[t].x * invN;
}

extern "C" void kernel_launch(void* const* d_in, const int* in_sizes, int n_in,
                              void* d_out, int out_size, void* d_ws, size_t ws_size,
                              hipStream_t stream) {
  const float* wav  = (const float*)d_in[0];
  const float* ph   = (const float*)d_in[1];
  const float* mask = (const float*)d_in[2];
  const size_t need = (size_t)BB * TT * CC * sizeof(__half2);  // 128 MB

  if (ws_size >= need) {
    // ws (A->B) aliases d_out; ws2 (B->C) lives in d_ws. Distinct kernels on
    // the same stream order the hazards.
    __half2* ws  = (__half2*)d_out;
    __half2* ws2 = (__half2*)d_ws;
    kA<<<dim3(BB * 64), dim3(NTHREADS), 0, stream>>>(wav, ws);
    kB<<<dim3(BB * 32), dim3(NTHREADS), 0, stream>>>(ws, ph, mask, ws2);
    kC<<<dim3(BB * 64), dim3(NTHREADS), 0, stream>>>(ws2, (float*)d_out);
  } else {
    ft_surrogate_fallback<<<dim3(BB * CC), dim3(NTHREADS), 0, stream>>>(
        wav, ph, mask, (float*)d_out);
  }
}

// Round 2
// 465.088 us; speedup vs baseline: 1.5221x; 1.3169x over previous
//
#include <hip/hip_runtime.h>
#include <hip/hip_fp16.h>
#include <math.h>

#define TT 8192
#define LOG2T 13
#define CC 64
#define BB 64
#define NTHREADS 256
#define TWO_PI 6.28318530717958647692f

// ============================================================================
// Four-step FFT: 8192 = N1(64) * N2(128).  t = n1 + 64*n2, k = 128*k1 + k2.
// LDS-free / barrier-free, and now (almost) transcendental-free:
//  - All FFT-stage twiddles and the radix-4 combine twiddles are 128th roots
//    of unity with COMPILE-TIME indices -> constexpr Taylor table, folded to
//    literals (kernels templated on the wave-uniform q so sq*j is constexpr).
//  - Output twiddles W8192^{±n1*k2} are geometric in the store loop index ->
//    1-2 sincos + complex-multiply recurrence instead of 32/64 sincos.
//  - Only genuinely-runtime sincos left: kB's phase replacement (data-dep).
// ws  (kernel A out, aliased onto d_out): [b][k2][n1][c]   (half2)
// ws2 (kernel B out, in d_ws):            [b][n1][k2][c]   (half2)
// Mask handling: masked-out channels skip phase replacement in B, so the
// round-trip FFT->IFFT reproduces the input.
// ============================================================================

// ---- compile-time twiddle machinery ----------------------------------------
constexpr double PI_D = 3.141592653589793238462643383279502884;
constexpr double ct_sin(double x) {  // |x| <= pi, Taylor
  double x2 = x * x, t = x, s = x;
  for (int k = 1; k <= 13; ++k) { t *= -x2 / ((2.0 * k) * (2.0 * k + 1.0)); s += t; }
  return s;
}
constexpr double ct_cos(double x) {
  double x2 = x * x, t = 1.0, s = 1.0;
  for (int k = 1; k <= 13; ++k) { t *= -x2 / ((2.0 * k - 1.0) * (2.0 * k)); s += t; }
  return s;
}
struct Tw128 { float c[128]; float s[128]; };
constexpr Tw128 mk_tw() {
  Tw128 t{};
  for (int k = 0; k < 128; ++k) {
    int kk = (k < 64) ? k : k - 128;             // reduce to [-pi, pi)
    double a = (2.0 * PI_D / 128.0) * kk;        // +angle; fwd uses -s
    t.c[k] = (float)ct_cos(a);
    t.s[k] = (float)ct_sin(a);
  }
  return t;
}
constexpr Tw128 TW = mk_tw();

constexpr int br5(int x) {
  return ((x & 1) << 4) | ((x & 2) << 2) | (x & 4) | ((x & 8) >> 2) | ((x & 16) >> 4);
}
constexpr int br6(int x) {
  return ((x & 1) << 5) | ((x & 2) << 3) | ((x & 4) << 1) |
         ((x & 8) >> 1) | ((x & 16) >> 3) | ((x & 32) >> 5);
}
constexpr int br7(int x) {
  return (br5(x & 31) << 2) | (((x >> 5) & 1) << 1) | ((x >> 6) & 1);
}

__device__ __forceinline__ float2 cmul(float2 a, float co, float si) {
  return make_float2(a.x * co - a.y * si, a.x * si + a.y * co);
}

// DIF stage over NB butterflies, span HLF; twiddle exp(-/+ i*pi*j/HLF).
// Table index k = (64/HLF)*j is compile-time after unrolling.
template<int HLF, int NB, bool INV>
__device__ __forceinline__ void dif_stage(float2* X) {
  #pragma unroll
  for (int m = 0; m < NB; ++m) {
    const int j = m & (HLF - 1);
    const int i1 = ((m & ~(HLF - 1)) << 1) | j;
    const int i2 = i1 + HLF;
    const int k = (64 / HLF) * j;
    const float2 u = X[i1], v = X[i2];
    X[i1] = make_float2(u.x + v.x, u.y + v.y);
    const float dx = u.x - v.x, dy = u.y - v.y;
    if (k == 0) {
      X[i2] = make_float2(dx, dy);
    } else {
      const float co = TW.c[k], si = INV ? TW.s[k] : -TW.s[k];
      X[i2] = make_float2(dx * co - dy * si, dx * si + dy * co);
    }
  }
}

// Inverse DIT stage (bitrev in -> natural out), twiddle exp(+i*pi*j/HLF).
template<int HLF, int NB>
__device__ __forceinline__ void dit_stage_inv(float2* X) {
  #pragma unroll
  for (int m = 0; m < NB; ++m) {
    const int j = m & (HLF - 1);
    const int i1 = ((m & ~(HLF - 1)) << 1) | j;
    const int i2 = i1 + HLF;
    const int k = (64 / HLF) * j;
    const float2 u = X[i1], w = X[i2];
    float tr, ti;
    if (k == 0) { tr = w.x; ti = w.y; }
    else { tr = w.x * TW.c[k] - w.y * TW.s[k]; ti = w.x * TW.s[k] + w.y * TW.c[k]; }
    X[i1] = make_float2(u.x + tr, u.y + ti);
    X[i2] = make_float2(u.x - tr, u.y - ti);
  }
}

// ---- Kernel A: per (b, n1): 64 channels x 128-pt forward FFT ---------------
template<int Q>
__device__ __forceinline__ void kA_impl(const float* __restrict__ wp,
                                        __half2* __restrict__ ws,
                                        size_t wbase, int n1) {
  constexpr int SQ = (Q == 0) ? 0 : (Q == 1) ? 2 : (Q == 2) ? 1 : 3;  // br2(Q)
  float2 X[32];
  // Radix-4 first step (stages hlf=64,32 fused) directly from global.
  #pragma unroll
  for (int j = 0; j < 32; ++j) {
    const float a  = wp[(size_t)(j      ) * (64 * CC)];
    const float bb = wp[(size_t)(j + 32) * (64 * CC)];
    const float cc = wp[(size_t)(j + 64) * (64 * CC)];
    const float dd = wp[(size_t)(j + 96) * (64 * CC)];
    float2 base;
    if constexpr (Q == 0)      base = make_float2((a + cc) + (bb + dd), 0.0f);
    else if constexpr (Q == 1) base = make_float2((a + cc) - (bb + dd), 0.0f);
    else if constexpr (Q == 2) base = make_float2(a - cc, dd - bb);  // (a-c)-i(b-d)
    else                       base = make_float2(a - cc, bb - dd);  // (a-c)+i(b-d)
    const int k = (SQ * j) & 127;  // W128^{-SQ*j}
    if (k == 0) X[j] = base;
    else X[j] = cmul(base, TW.c[k], -TW.s[k]);
  }
  // 5 register-resident DIF stages (compile-time twiddles).
  dif_stage<16, 16, false>(X); dif_stage<8, 16, false>(X);
  dif_stage<4, 16, false>(X);  dif_stage<2, 16, false>(X);
  dif_stage<1, 16, false>(X);
  // Output twiddle W8192^{-n1*k2}, k2 = 4r + SQ, position m = br5(r).
  // Geometric recurrence: w *= exp(-i*2pi*4*n1/8192) per r.
  float cd, sd, c0, s0;
  __sincosf(-(TWO_PI / 2048.0f) * (float)n1, &sd, &cd);
  __sincosf(-(TWO_PI / 8192.0f) * (float)(n1 * SQ), &s0, &c0);
  float wc = c0, wsn = s0;
  #pragma unroll
  for (int r = 0; r < 32; ++r) {
    const int m = br5(r);
    const float2 v = cmul(X[m], wc, wsn);
    ws[wbase + (size_t)(4 * r + SQ) * 4096] = __floats2half2_rn(v.x, v.y);
    const float nc = wc * cd - wsn * sd;
    wsn = wc * sd + wsn * cd; wc = nc;
  }
}

__global__ __launch_bounds__(NTHREADS) void kA(const float* __restrict__ wav,
                                               __half2* __restrict__ ws) {
  const int b = blockIdx.x >> 6, n1 = blockIdx.x & 63;
  const int tid = threadIdx.x, c = tid & 63, q = tid >> 6;  // q wave-uniform
  const float* wp = wav + ((size_t)b * TT + n1) * CC + c;
  const size_t wbase = (size_t)b * (128 * 4096) + (size_t)n1 * 64 + c;
  switch (q) {
    case 0: kA_impl<0>(wp, ws, wbase, n1); break;
    case 1: kA_impl<1>(wp, ws, wbase, n1); break;
    case 2: kA_impl<2>(wp, ws, wbase, n1); break;
    default: kA_impl<3>(wp, ws, wbase, n1); break;
  }
}

// ---- Kernel B: per (b, k2, c): 64-pt fwd FFT, phase replace, inv FFT -------
__global__ __launch_bounds__(NTHREADS) void kB(const __half2* __restrict__ ws,
                                               const float* __restrict__ ph,
                                               const float* __restrict__ mask,
                                               __half2* __restrict__ ws2) {
  const int b = blockIdx.x >> 5;
  const int k2 = ((blockIdx.x & 31) << 2) | (threadIdx.x >> 6);  // wave-uniform
  const int c = threadIdx.x & 63;

  const __half2* rp = ws + ((size_t)(b * 128 + k2) * 64) * 64 + c;
  float2 X[64];
  #pragma unroll
  for (int n1 = 0; n1 < 64; ++n1) X[n1] = __half22float2(rp[(size_t)n1 * 64]);

  // forward 64-pt DIF (natural in -> bitrev out), compile-time twiddles
  dif_stage<32, 32, false>(X); dif_stage<16, 32, false>(X);
  dif_stage<8, 32, false>(X);  dif_stage<4, 32, false>(X);
  dif_stage<2, 32, false>(X);  dif_stage<1, 32, false>(X);

  // Pointwise: position p holds k1 = br6(p); full freq k = 128*k1 + k2.
  const float msk = mask[(b << 6) + c];
  if (msk < 0.5f) {
    const size_t pbase = ((size_t)b * TT + k2) * CC + c;
    #pragma unroll
    for (int p = 0; p < 64; ++p) {
      const int k1 = br6(p);
      const float phi = ph[pbase + ((size_t)k1 << 13)];
      const float2 v = X[p];
      const float amp = sqrtf(v.x * v.x + v.y * v.y);
      float s, co;
      __sincosf(TWO_PI * phi, &s, &co);
      X[p] = make_float2(amp * co, amp * s);
    }
  }

  // inverse 64-pt DIT (bitrev in -> natural out), compile-time twiddles
  dit_stage_inv<1, 32>(X);  dit_stage_inv<2, 32>(X);
  dit_stage_inv<4, 32>(X);  dit_stage_inv<8, 32>(X);
  dit_stage_inv<16, 32>(X); dit_stage_inv<32, 32>(X);

  // Inverse outer twiddle W8192^{+n1*k2} via geometric recurrence over n1.
  float cd, sd;
  __sincosf((TWO_PI / 8192.0f) * (float)k2, &sd, &cd);
  float wc = 1.0f, wsn = 0.0f;
  __half2* op = ws2 + ((size_t)b * 64 * 128 + k2) * 64 + c;
  #pragma unroll
  for (int n1 = 0; n1 < 64; ++n1) {
    const float2 v = cmul(X[n1], wc, wsn);
    op[(size_t)n1 * (128 * 64)] = __floats2half2_rn(v.x, v.y);
    const float nc = wc * cd - wsn * sd;
    wsn = wc * sd + wsn * cd; wc = nc;
  }
}

// ---- Kernel C: per (b, n1): 64 channels x 128-pt inverse FFT ---------------
template<int Q>
__device__ __forceinline__ void kC_impl(const __half2* __restrict__ rp,
                                        float* __restrict__ out, size_t obase) {
  constexpr int SQ = (Q == 0) ? 0 : (Q == 1) ? 2 : (Q == 2) ? 1 : 3;
  float2 X[32];
  // Radix-4 first step from global, W = e^{+i...}
  #pragma unroll
  for (int j = 0; j < 32; ++j) {
    const float2 a  = __half22float2(rp[(size_t)(j      ) * 64]);
    const float2 bb = __half22float2(rp[(size_t)(j + 32) * 64]);
    const float2 cc = __half22float2(rp[(size_t)(j + 64) * 64]);
    const float2 dd = __half22float2(rp[(size_t)(j + 96) * 64]);
    float2 base;
    if constexpr (Q == 0)
      base = make_float2((a.x + cc.x) + (bb.x + dd.x), (a.y + cc.y) + (bb.y + dd.y));
    else if constexpr (Q == 1)
      base = make_float2((a.x + cc.x) - (bb.x + dd.x), (a.y + cc.y) - (bb.y + dd.y));
    else if constexpr (Q == 2)  // (a-c) + i(b-d)
      base = make_float2((a.x - cc.x) - (bb.y - dd.y), (a.y - cc.y) + (bb.x - dd.x));
    else                        // (a-c) - i(b-d)
      base = make_float2((a.x - cc.x) + (bb.y - dd.y), (a.y - cc.y) - (bb.x - dd.x));
    const int k = (SQ * j) & 127;  // W128^{+SQ*j}
    if (k == 0) X[j] = base;
    else X[j] = cmul(base, TW.c[k], TW.s[k]);
  }
  // 5 register-resident inverse DIF stages
  dif_stage<16, 16, true>(X); dif_stage<8, 16, true>(X);
  dif_stage<4, 16, true>(X);  dif_stage<2, 16, true>(X);
  dif_stage<1, 16, true>(X);
  // Position p holds n2 = br7(p): out[b][n1 + 64*n2][c] = Re * (1/8192)
  #pragma unroll
  for (int m = 0; m < 32; ++m) {
    const int p = (Q << 5) | m;
    const int n2 = br7(p);
    out[obase + ((size_t)n2 << 6) * CC] = X[m].x * (1.0f / 8192.0f);
  }
}

__global__ __launch_bounds__(NTHREADS) void kC(const __half2* __restrict__ ws2,
                                               float* __restrict__ out) {
  const int b = blockIdx.x >> 6, n1 = blockIdx.x & 63;
  const int tid = threadIdx.x, c = tid & 63, q = tid >> 6;
  const __half2* rp = ws2 + (size_t)blockIdx.x * 8192 + c;  // [k2][c]
  const size_t obase = (size_t)b * (TT * CC) + (size_t)n1 * CC + c;
  switch (q) {
    case 0: kC_impl<0>(rp, out, obase); break;
    case 1: kC_impl<1>(rp, out, obase); break;
    case 2: kC_impl<2>(rp, out, obase); break;
    default: kC_impl<3>(rp, out, obase); break;
  }
}

// ---- Fallback (R1 single-kernel, correct but slow) if ws is too small ----
__global__ __launch_bounds__(NTHREADS) void ft_surrogate_fallback(
    const float* __restrict__ wav, const float* __restrict__ ph,
    const float* __restrict__ mask, float* __restrict__ out) {
  const int bc = blockIdx.x;
  const int c = bc & (CC - 1);
  const int b = bc >> 6;
  const int tid = threadIdx.x;
  const size_t base = (size_t)b * TT * CC + (size_t)c;
  const float m = mask[bc];
  if (!(m < 0.5f)) {
    for (int t = tid; t < TT; t += NTHREADS)
      out[base + (size_t)t * CC] = wav[base + (size_t)t * CC];
    return;
  }
  __shared__ float2 X[TT];
  for (int t = tid; t < TT; t += NTHREADS)
    X[t] = make_float2(wav[base + (size_t)t * CC], 0.0f);
  __syncthreads();
  for (int len = TT, hlf = TT >> 1; len >= 2; len >>= 1, hlf >>= 1) {
    const float ang_scale = -TWO_PI / (float)len;
    for (int it = 0; it < (TT / 2) / NTHREADS; ++it) {
      const int m2 = tid + it * NTHREADS;
      const int j = m2 & (hlf - 1);
      const int i1 = ((m2 & ~(hlf - 1)) << 1) | j;
      const int i2 = i1 + hlf;
      float2 u = X[i1], v = X[i2];
      float ar = u.x + v.x, ai = u.y + v.y;
      float br = u.x - v.x, bi = u.y - v.y;
      float s, cth;
      __sincosf(ang_scale * (float)j, &s, &cth);
      X[i1] = make_float2(ar, ai);
      X[i2] = make_float2(br * cth - bi * s, br * s + bi * cth);
    }
    __syncthreads();
  }
  for (int p = tid; p < TT; p += NTHREADS) {
    const int k = (int)(__brev((unsigned)p) >> (32 - LOG2T));
    float2 v = X[p];
    float amp = sqrtf(v.x * v.x + v.y * v.y);
    float phi = ph[(size_t)b * TT * CC + (size_t)k * CC + (size_t)c];
    float s, cth;
    __sincosf(TWO_PI * phi, &s, &cth);
    X[p] = make_float2(amp * cth, amp * s);
  }
  __syncthreads();
  for (int len = 2, hlf = 1; len <= TT; len <<= 1, hlf <<= 1) {
    const float ang_scale = TWO_PI / (float)len;
    for (int it = 0; it < (TT / 2) / NTHREADS; ++it) {
      const int m2 = tid + it * NTHREADS;
      const int j = m2 & (hlf - 1);
      const int i1 = ((m2 & ~(hlf - 1)) << 1) | j;
      const int i2 = i1 + hlf;
      float s, cth;
      __sincosf(ang_scale * (float)j, &s, &cth);
      float2 u = X[i1], w = X[i2];
      float vr = w.x * cth - w.y * s;
      float vi = w.x * s + w.y * cth;
      X[i1] = make_float2(u.x + vr, u.y + vi);
      X[i2] = make_float2(u.x - vr, u.y - vi);
    }
    __syncthreads();
  }
  const float invN = 1.0f / (float)TT;
  for (int t = tid; t < TT; t += NTHREADS)
    out[base + (size_t)t * CC] = X[t].x * invN;
}

extern "C" void kernel_launch(void* const* d_in, const int* in_sizes, int n_in,
                              void* d_out, int out_size, void* d_ws, size_t ws_size,
                              hipStream_t stream) {
  const float* wav  = (const float*)d_in[0];
  const float* ph   = (const float*)d_in[1];
  const float* mask = (const float*)d_in[2];
  const size_t need = (size_t)BB * TT * CC * sizeof(__half2);  // 128 MB

  if (ws_size >= need) {
    // ws (A->B) aliases d_out; ws2 (B->C) lives in d_ws. Distinct kernels on
    // the same stream order the hazards.
    __half2* ws  = (__half2*)d_out;
    __half2* ws2 = (__half2*)d_ws;
    kA<<<dim3(BB * 64), dim3(NTHREADS), 0, stream>>>(wav, ws);
    kB<<<dim3(BB * 32), dim3(NTHREADS), 0, stream>>>(ws, ph, mask, ws2);
    kC<<<dim3(BB * 64), dim3(NTHREADS), 0, stream>>>(ws2, (float*)d_out);
  } else {
    ft_surrogate_fallback<<<dim3(BB * CC), dim3(NTHREADS), 0, stream>>>(
        wav, ph, mask, (float*)d_out);
  }
}

// Round 3
// 461.826 us; speedup vs baseline: 1.5328x; 1.0071x over previous
//
#include <hip/hip_runtime.h>
#include <hip/hip_fp16.h>
#include <math.h>

#define TT 8192
#define LOG2T 13
#define CC 64
#define BB 64
#define NTHREADS 256
#define TWO_PI 6.28318530717958647692f

// ============================================================================
// Four-step FFT: 8192 = N1(64) * N2(128).  t = n1 + 64*n2, k = 128*k1 + k2.
// LDS-free / barrier-free / transcendental-lean, now LANE-COOPERATIVE:
//  - kA/kC: wave = 16 channels x 4 q-lanes. Each lane loads only its 32 rows
//    (was 128 with 4x redundancy); the two cross-block radix-4 stages become
//    two __shfl_xor exchanges. Per-lane combine twiddle W128^{SQ*r} via raw
//    v_sin/v_cos (revolutions input).
//  - kB: wave = 32 channels x 2 half-lanes; lane pair (l, l^32) shares one
//    channel's 64-pt transform, 32 points each (64 data VGPRs, was 128).
//    Only first fwd / last inv stage cross halves (compile-time twiddles).
//    Phase sincos = raw v_sin/v_cos on phi (already in revolutions).
// ws  (kernel A out, aliased onto d_out): [b][k2][n1][c]   (half2)
// ws2 (kernel B out, in d_ws):            [b][n1][k2][c]   (half2)
// Mask handling: masked-out channels skip phase replacement in B, so the
// round-trip FFT->IFFT reproduces the input.
// ============================================================================

// ---- compile-time twiddle machinery ----------------------------------------
constexpr double PI_D = 3.141592653589793238462643383279502884;
constexpr double ct_sin(double x) {  // |x| <= pi, Taylor
  double x2 = x * x, t = x, s = x;
  for (int k = 1; k <= 13; ++k) { t *= -x2 / ((2.0 * k) * (2.0 * k + 1.0)); s += t; }
  return s;
}
constexpr double ct_cos(double x) {
  double x2 = x * x, t = 1.0, s = 1.0;
  for (int k = 1; k <= 13; ++k) { t *= -x2 / ((2.0 * k - 1.0) * (2.0 * k)); s += t; }
  return s;
}
struct Tw128 { float c[128]; float s[128]; };
constexpr Tw128 mk_tw() {
  Tw128 t{};
  for (int k = 0; k < 128; ++k) {
    int kk = (k < 64) ? k : k - 128;             // reduce to [-pi, pi)
    double a = (2.0 * PI_D / 128.0) * kk;        // +angle; fwd uses -s
    t.c[k] = (float)ct_cos(a);
    t.s[k] = (float)ct_sin(a);
  }
  return t;
}
constexpr Tw128 TW = mk_tw();

constexpr int br5(int x) {
  return ((x & 1) << 4) | ((x & 2) << 2) | (x & 4) | ((x & 8) >> 2) | ((x & 16) >> 4);
}

__device__ __forceinline__ float2 cmul(float2 a, float co, float si) {
  return make_float2(a.x * co - a.y * si, a.x * si + a.y * co);
}
// raw HW sin/cos: input in REVOLUTIONS (D = sin/cos(S0 * 2pi))
__device__ __forceinline__ float hw_sin(float f) {
  float r; asm("v_sin_f32 %0, %1" : "=v"(r) : "v"(f)); return r;
}
__device__ __forceinline__ float hw_cos(float f) {
  float r; asm("v_cos_f32 %0, %1" : "=v"(r) : "v"(f)); return r;
}

// DIF stage over NB butterflies, span HLF; twiddle exp(-/+ i*pi*j/HLF).
template<int HLF, int NB, bool INV>
__device__ __forceinline__ void dif_stage(float2* X) {
  #pragma unroll
  for (int m = 0; m < NB; ++m) {
    const int j = m & (HLF - 1);
    const int i1 = ((m & ~(HLF - 1)) << 1) | j;
    const int i2 = i1 + HLF;
    const int k = (64 / HLF) * j;
    const float2 u = X[i1], v = X[i2];
    X[i1] = make_float2(u.x + v.x, u.y + v.y);
    const float dx = u.x - v.x, dy = u.y - v.y;
    if (k == 0) {
      X[i2] = make_float2(dx, dy);
    } else {
      const float co = TW.c[k], si = INV ? TW.s[k] : -TW.s[k];
      X[i2] = make_float2(dx * co - dy * si, dx * si + dy * co);
    }
  }
}

// Inverse DIT stage (bitrev in -> natural out), twiddle exp(+i*pi*j/HLF).
template<int HLF, int NB>
__device__ __forceinline__ void dit_stage_inv(float2* X) {
  #pragma unroll
  for (int m = 0; m < NB; ++m) {
    const int j = m & (HLF - 1);
    const int i1 = ((m & ~(HLF - 1)) << 1) | j;
    const int i2 = i1 + HLF;
    const int k = (64 / HLF) * j;
    const float2 u = X[i1], w = X[i2];
    float tr, ti;
    if (k == 0) { tr = w.x; ti = w.y; }
    else { tr = w.x * TW.c[k] - w.y * TW.s[k]; ti = w.x * TW.s[k] + w.y * TW.c[k]; }
    X[i1] = make_float2(u.x + tr, u.y + ti);
    X[i2] = make_float2(u.x - tr, u.y - ti);
  }
}

// ---- Kernel A: per (b, n1): 64 channels x 128-pt forward FFT ---------------
// Wave = 16 channels x 4 q-lanes (lane bits 4..5 = q). Lane q loads rows
// n2 = 32q..32q+31; radix-4 cross combine via shfl_xor(32), shfl_xor(16).
__global__ __launch_bounds__(NTHREADS) void kA(const float* __restrict__ wav,
                                               __half2* __restrict__ ws) {
  const int b = blockIdx.x >> 6, n1 = blockIdx.x & 63;
  const int tid = threadIdx.x, w = tid >> 6, l = tid & 63;
  const int q = l >> 4, cl = l & 15, c = (w << 4) | cl;
  const int SQ = ((q & 1) << 1) | (q >> 1);       // br2(q): {0,2,1,3}
  const bool hiQ = (l & 32) != 0, loQ = (l & 16) != 0;

  const float* wp = wav + ((size_t)b * TT + n1) * CC + c + (size_t)q * (32 * 64 * CC);
  float x[32];
  #pragma unroll
  for (int r = 0; r < 32; ++r) x[r] = wp[(size_t)r * (64 * CC)];

  // cross radix-4 combine + per-lane combine twiddle W128^{-SQ*r}
  const float sqn = (float)SQ * (-1.0f / 128.0f);
  float2 X[32];
  #pragma unroll
  for (int r = 0; r < 32; ++r) {
    const float t = __shfl_xor(x[r], 32, 64);
    const float u = hiQ ? (t - x[r]) : (x[r] + t);
    const float t2 = __shfl_xor(u, 16, 64);
    const float re = hiQ ? (loQ ? t2 : u) : (loQ ? (t2 - u) : (u + t2));
    const float im = hiQ ? (loQ ? u : -t2) : 0.0f;
    if (r == 0) { X[0] = make_float2(re, im); }
    else {
      const float arg = sqn * (float)r;
      const float si = hw_sin(arg), co = hw_cos(arg);
      X[r] = make_float2(re * co - im * si, re * si + im * co);
    }
  }

  // 5 register-resident DIF stages (compile-time twiddles).
  dif_stage<16, 16, false>(X); dif_stage<8, 16, false>(X);
  dif_stage<4, 16, false>(X);  dif_stage<2, 16, false>(X);
  dif_stage<1, 16, false>(X);

  // Output twiddle W8192^{-n1*k2}, k2 = 4r + SQ, position m = br5(r).
  float cd, sd, c0, s0;
  __sincosf(-(TWO_PI / 2048.0f) * (float)n1, &sd, &cd);
  __sincosf(-(TWO_PI / 8192.0f) * (float)(n1 * SQ), &s0, &c0);
  float wc = c0, wsn = s0;
  __half2* wsp = ws + (size_t)b * (128 * 4096) + (size_t)n1 * 64 + c +
                 (size_t)SQ * 4096;
  #pragma unroll
  for (int r = 0; r < 32; ++r) {
    const int m = br5(r);
    const float2 v = cmul(X[m], wc, wsn);
    wsp[(size_t)r * 16384] = __floats2half2_rn(v.x, v.y);
    const float nc = wc * cd - wsn * sd;
    wsn = wc * sd + wsn * cd; wc = nc;
  }
}

// ---- Kernel B: per (b, k2, c): 64-pt fwd FFT, phase replace, inv FFT -------
// Lane pair (l, l^32) shares one channel; each lane holds 32 of the 64 points.
__global__ __launch_bounds__(NTHREADS) void kB(const __half2* __restrict__ ws,
                                               const float* __restrict__ ph,
                                               const float* __restrict__ mask,
                                               __half2* __restrict__ ws2) {
  const int b = blockIdx.x >> 6, g = blockIdx.x & 63;
  const int tid = threadIdx.x, w = tid >> 6, l = tid & 63;
  const int h = l >> 5, cl = l & 31;
  const int k2 = (g << 1) | (w >> 1);             // wave-uniform
  const int c = ((w & 1) << 5) | cl;
  const bool hb = (l & 32) != 0;

  const __half2* rp = ws + ((size_t)(b * 128 + k2) * 64 + (size_t)(32 * h)) * 64 + c;
  float2 X[32];
  #pragma unroll
  for (int r = 0; r < 32; ++r) X[r] = __half22float2(rp[(size_t)r * 64]);

  // fwd cross stage (hlf=32): pair (r, r+32); upper half gets (u-v)*W64^{-r}
  #pragma unroll
  for (int r = 0; r < 32; ++r) {
    const float tre = __shfl_xor(X[r].x, 32, 64);
    const float tim = __shfl_xor(X[r].y, 32, 64);
    const float sre = X[r].x + tre, sim = X[r].y + tim;
    const float dre = tre - X[r].x, dim = tim - X[r].y;
    const float co = TW.c[2 * r], si = -TW.s[2 * r];
    const float wre = dre * co - dim * si;
    const float wim = dre * si + dim * co;
    X[r].x = hb ? wre : sre;
    X[r].y = hb ? wim : sim;
  }
  // 5 local DIF stages: each half is an independent 32-pt DFT.
  dif_stage<16, 16, false>(X); dif_stage<8, 16, false>(X);
  dif_stage<4, 16, false>(X);  dif_stage<2, 16, false>(X);
  dif_stage<1, 16, false>(X);

  // Pointwise: reg r holds k1 = 2*br5(r) + h; full freq k = 128*k1 + k2.
  const float msk = mask[(b << 6) + c];
  if (msk < 0.5f) {
    const float* pp = ph + ((size_t)b * TT + k2) * CC + c + ((size_t)h << 13);
    #pragma unroll
    for (int r = 0; r < 32; ++r) {
      const float phi = pp[(size_t)br5(r) << 14];
      const float2 v = X[r];
      const float amp = sqrtf(v.x * v.x + v.y * v.y);
      const float si = hw_sin(phi), co = hw_cos(phi);  // phi in revolutions
      X[r] = make_float2(amp * co, amp * si);
    }
  }

  // inverse: 5 local DIT stages (bitrev in -> natural out within half)...
  dit_stage_inv<1, 16>(X);  dit_stage_inv<2, 16>(X);
  dit_stage_inv<4, 16>(X);  dit_stage_inv<8, 16>(X);
  dit_stage_inv<16, 16>(X);
  // ...then cross stage (hlf=32): t = w*W64^{+r}; low = u+t, high = u-t.
  #pragma unroll
  for (int r = 0; r < 32; ++r) {
    const float tre = __shfl_xor(X[r].x, 32, 64);
    const float tim = __shfl_xor(X[r].y, 32, 64);
    const float wre_ = hb ? X[r].x : tre, wim_ = hb ? X[r].y : tim;
    const float ure = hb ? tre : X[r].x, uim = hb ? tim : X[r].y;
    const float co = TW.c[2 * r], si = TW.s[2 * r];
    const float twr = wre_ * co - wim_ * si;
    const float twi = wre_ * si + wim_ * co;
    X[r].x = hb ? (ure - twr) : (ure + twr);
    X[r].y = hb ? (uim - twi) : (uim + twi);
  }

  // Inverse outer twiddle W8192^{+n1*k2}, n1 = 32h + r; recurrence over r.
  float cd, sd, c0, s0;
  __sincosf((TWO_PI / 8192.0f) * (float)k2, &sd, &cd);
  __sincosf((TWO_PI / 256.0f) * (float)(h * k2), &s0, &c0);  // 32*k2/8192
  float wc = c0, wsn = s0;
  __half2* op = ws2 + ((size_t)b * 8192 + k2) * 64 + c + (size_t)(32 * h) * 8192;
  #pragma unroll
  for (int r = 0; r < 32; ++r) {
    const float2 v = cmul(X[r], wc, wsn);
    op[(size_t)r * 8192] = __floats2half2_rn(v.x, v.y);
    const float nc = wc * cd - wsn * sd;
    wsn = wc * sd + wsn * cd; wc = nc;
  }
}

// ---- Kernel C: per (b, n1): 64 channels x 128-pt inverse FFT ---------------
__global__ __launch_bounds__(NTHREADS) void kC(const __half2* __restrict__ ws2,
                                               float* __restrict__ out) {
  const int b = blockIdx.x >> 6, n1 = blockIdx.x & 63;
  const int tid = threadIdx.x, w = tid >> 6, l = tid & 63;
  const int q = l >> 4, cl = l & 15, c = (w << 4) | cl;
  const int SQ = ((q & 1) << 1) | (q >> 1);
  const bool hiQ = (l & 32) != 0, loQ = (l & 16) != 0;

  const __half2* rp = ws2 + (size_t)blockIdx.x * 8192 + (size_t)(32 * q) * 64 + c;
  float2 x[32];
  #pragma unroll
  for (int r = 0; r < 32; ++r) x[r] = __half22float2(rp[(size_t)r * 64]);

  // cross radix-4 combine (inverse), per-lane twiddle W128^{+SQ*r}
  const float sqp = (float)SQ * (1.0f / 128.0f);
  float2 X[32];
  #pragma unroll
  for (int r = 0; r < 32; ++r) {
    const float tre = __shfl_xor(x[r].x, 32, 64);
    const float tim = __shfl_xor(x[r].y, 32, 64);
    const float ure = hiQ ? (tre - x[r].x) : (x[r].x + tre);
    const float uim = hiQ ? (tim - x[r].y) : (x[r].y + tim);
    const float t2re = __shfl_xor(ure, 16, 64);
    const float t2im = __shfl_xor(uim, 16, 64);
    const float re = hiQ ? (loQ ? (t2re + uim) : (ure - t2im))
                         : (loQ ? (t2re - ure) : (ure + t2re));
    const float im = hiQ ? (loQ ? (t2im - ure) : (uim + t2re))
                         : (loQ ? (t2im - uim) : (uim + t2im));
    if (r == 0) { X[0] = make_float2(re, im); }
    else {
      const float arg = sqp * (float)r;
      const float si = hw_sin(arg), co = hw_cos(arg);
      X[r] = make_float2(re * co - im * si, re * si + im * co);
    }
  }

  // 5 register-resident inverse DIF stages
  dif_stage<16, 16, true>(X); dif_stage<8, 16, true>(X);
  dif_stage<4, 16, true>(X);  dif_stage<2, 16, true>(X);
  dif_stage<1, 16, true>(X);

  // Position m holds n2 = 4*br5(m) + SQ: out[b][n1 + 64*n2][c] = Re / 8192
  float* op = out + (size_t)b * (TT * CC) + (size_t)n1 * CC + c + (size_t)SQ * 4096;
  #pragma unroll
  for (int r = 0; r < 32; ++r) {
    const int m = br5(r);  // n2 = 4*br5(m)+SQ <=> iterate m, offset br5(m)... 
    // iterate r over regs in bit-rev store order: reg m=br5(r) -> n2 = 4r + SQ
    op[(size_t)r * 16384] = X[m].x * (1.0f / 8192.0f);
  }
}

// ---- Fallback (R1 single-kernel, correct but slow) if ws is too small ----
__global__ __launch_bounds__(NTHREADS) void ft_surrogate_fallback(
    const float* __restrict__ wav, const float* __restrict__ ph,
    const float* __restrict__ mask, float* __restrict__ out) {
  const int bc = blockIdx.x;
  const int c = bc & (CC - 1);
  const int b = bc >> 6;
  const int tid = threadIdx.x;
  const size_t base = (size_t)b * TT * CC + (size_t)c;
  const float m = mask[bc];
  if (!(m < 0.5f)) {
    for (int t = tid; t < TT; t += NTHREADS)
      out[base + (size_t)t * CC] = wav[base + (size_t)t * CC];
    return;
  }
  __shared__ float2 X[TT];
  for (int t = tid; t < TT; t += NTHREADS)
    X[t] = make_float2(wav[base + (size_t)t * CC], 0.0f);
  __syncthreads();
  for (int len = TT, hlf = TT >> 1; len >= 2; len >>= 1, hlf >>= 1) {
    const float ang_scale = -TWO_PI / (float)len;
    for (int it = 0; it < (TT / 2) / NTHREADS; ++it) {
      const int m2 = tid + it * NTHREADS;
      const int j = m2 & (hlf - 1);
      const int i1 = ((m2 & ~(hlf - 1)) << 1) | j;
      const int i2 = i1 + hlf;
      float2 u = X[i1], v = X[i2];
      float ar = u.x + v.x, ai = u.y + v.y;
      float br = u.x - v.x, bi = u.y - v.y;
      float s, cth;
      __sincosf(ang_scale * (float)j, &s, &cth);
      X[i1] = make_float2(ar, ai);
      X[i2] = make_float2(br * cth - bi * s, br * s + bi * cth);
    }
    __syncthreads();
  }
  for (int p = tid; p < TT; p += NTHREADS) {
    const int k = (int)(__brev((unsigned)p) >> (32 - LOG2T));
    float2 v = X[p];
    float amp = sqrtf(v.x * v.x + v.y * v.y);
    float phi = ph[(size_t)b * TT * CC + (size_t)k * CC + (size_t)c];
    float s, cth;
    __sincosf(TWO_PI * phi, &s, &cth);
    X[p] = make_float2(amp * cth, amp * s);
  }
  __syncthreads();
  for (int len = 2, hlf = 1; len <= TT; len <<= 1, hlf <<= 1) {
    const float ang_scale = TWO_PI / (float)len;
    for (int it = 0; it < (TT / 2) / NTHREADS; ++it) {
      const int m2 = tid + it * NTHREADS;
      const int j = m2 & (hlf - 1);
      const int i1 = ((m2 & ~(hlf - 1)) << 1) | j;
      const int i2 = i1 + hlf;
      float s, cth;
      __sincosf(ang_scale * (float)j, &s, &cth);
      float2 u = X[i1], w = X[i2];
      float vr = w.x * cth - w.y * s;
      float vi = w.x * s + w.y * cth;
      X[i1] = make_float2(u.x + vr, u.y + vi);
      X[i2] = make_float2(u.x - vr, u.y - vi);
    }
    __syncthreads();
  }
  const float invN = 1.0f / (float)TT;
  for (int t = tid; t < TT; t += NTHREADS)
    out[base + (size_t)t * CC] = X[t].x * invN;
}

extern "C" void kernel_launch(void* const* d_in, const int* in_sizes, int n_in,
                              void* d_out, int out_size, void* d_ws, size_t ws_size,
                              hipStream_t stream) {
  const float* wav  = (const float*)d_in[0];
  const float* ph   = (const float*)d_in[1];
  const float* mask = (const float*)d_in[2];
  const size_t need = (size_t)BB * TT * CC * sizeof(__half2);  // 128 MB

  if (ws_size >= need) {
    // ws (A->B) aliases d_out; ws2 (B->C) lives in d_ws. Distinct kernels on
    // the same stream order the hazards.
    __half2* ws  = (__half2*)d_out;
    __half2* ws2 = (__half2*)d_ws;
    kA<<<dim3(BB * 64), dim3(NTHREADS), 0, stream>>>(wav, ws);
    kB<<<dim3(BB * 64), dim3(NTHREADS), 0, stream>>>(ws, ph, mask, ws2);
    kC<<<dim3(BB * 64), dim3(NTHREADS), 0, stream>>>(ws2, (float*)d_out);
  } else {
    ft_surrogate_fallback<<<dim3(BB * CC), dim3(NTHREADS), 0, stream>>>(
        wav, ph, mask, (float*)d_out);
  }
}

// Round 4
// 452.427 us; speedup vs baseline: 1.5647x; 1.0208x over previous
//
#include <hip/hip_runtime.h>
#include <hip/hip_fp16.h>
#include <math.h>

#define TT 8192
#define LOG2T 13
#define CC 64
#define BB 64
#define NTHREADS 256
#define TWO_PI 6.28318530717958647692f

// ============================================================================
// Four-step FFT: 8192 = N1(64) * N2(128).  t = n1 + 64*n2, k = 128*k1 + k2.
//  - kA/kC (unchanged from R3): LDS-free lane-cooperative 128-pt FFTs.
//  - kB (NEW): the 64-pt fwd/inv transforms are 64x64x64 matmuls -> MFMA.
//      Y[k1][c] = sum_n1 F[k1][n1] X[n1][c],  F = W64^{-k1*n1} (symmetric!)
//      Z[n1][c] = sum_k1 G[n1][k1] Y[k1][c],  G = conj(F) -> frag sign-flips.
//    Complex matmul via 4 real accumulating v_mfma_f32_16x16x16_f16 chains.
//    X staged global->LDS [n1][c] stride 66 (2 lanes/bank, conflict-free);
//    mid Y roundtrip through 2nd LDS buffer (cross-wave K exchange).
//    Direct DFT kills all bit-reversal + cross-lane shuffles + stage twiddles.
// ws  (kernel A out, aliased onto d_out): [b][k2][n1][c]   (half2)
// ws2 (kernel B out, in d_ws):            [b][n1][k2][c]   (half2)
// Mask handling: masked-out channels skip phase replacement in B, so the
// round-trip DFT->IDFT (x64, normalized in kC by 1/8192) reproduces input.
// ============================================================================

// ---- compile-time twiddle machinery (kA/kC) --------------------------------
constexpr double PI_D = 3.141592653589793238462643383279502884;
constexpr double ct_sin(double x) {  // |x| <= pi, Taylor
  double x2 = x * x, t = x, s = x;
  for (int k = 1; k <= 13; ++k) { t *= -x2 / ((2.0 * k) * (2.0 * k + 1.0)); s += t; }
  return s;
}
constexpr double ct_cos(double x) {
  double x2 = x * x, t = 1.0, s = 1.0;
  for (int k = 1; k <= 13; ++k) { t *= -x2 / ((2.0 * k - 1.0) * (2.0 * k)); s += t; }
  return s;
}
struct Tw128 { float c[128]; float s[128]; };
constexpr Tw128 mk_tw() {
  Tw128 t{};
  for (int k = 0; k < 128; ++k) {
    int kk = (k < 64) ? k : k - 128;             // reduce to [-pi, pi)
    double a = (2.0 * PI_D / 128.0) * kk;        // +angle; fwd uses -s
    t.c[k] = (float)ct_cos(a);
    t.s[k] = (float)ct_sin(a);
  }
  return t;
}
constexpr Tw128 TW = mk_tw();

constexpr int br5(int x) {
  return ((x & 1) << 4) | ((x & 2) << 2) | (x & 4) | ((x & 8) >> 2) | ((x & 16) >> 4);
}

__device__ __forceinline__ float2 cmul(float2 a, float co, float si) {
  return make_float2(a.x * co - a.y * si, a.x * si + a.y * co);
}
// raw HW sin/cos: input in REVOLUTIONS (D = sin/cos(S0 * 2pi))
__device__ __forceinline__ float hw_sin(float f) {
  float r; asm("v_sin_f32 %0, %1" : "=v"(r) : "v"(f)); return r;
}
__device__ __forceinline__ float hw_cos(float f) {
  float r; asm("v_cos_f32 %0, %1" : "=v"(r) : "v"(f)); return r;
}

// DIF stage over NB butterflies, span HLF; twiddle exp(-/+ i*pi*j/HLF).
template<int HLF, int NB, bool INV>
__device__ __forceinline__ void dif_stage(float2* X) {
  #pragma unroll
  for (int m = 0; m < NB; ++m) {
    const int j = m & (HLF - 1);
    const int i1 = ((m & ~(HLF - 1)) << 1) | j;
    const int i2 = i1 + HLF;
    const int k = (64 / HLF) * j;
    const float2 u = X[i1], v = X[i2];
    X[i1] = make_float2(u.x + v.x, u.y + v.y);
    const float dx = u.x - v.x, dy = u.y - v.y;
    if (k == 0) {
      X[i2] = make_float2(dx, dy);
    } else {
      const float co = TW.c[k], si = INV ? TW.s[k] : -TW.s[k];
      X[i2] = make_float2(dx * co - dy * si, dx * si + dy * co);
    }
  }
}

// ---- MFMA helpers (kB) ------------------------------------------------------
typedef __attribute__((ext_vector_type(4))) _Float16 v4h;
typedef __attribute__((ext_vector_type(4))) float v4f;
typedef __attribute__((ext_vector_type(2))) unsigned int u32x2;

__device__ __forceinline__ v4h mk4h(unsigned int lo, unsigned int hi) {
  u32x2 u; u.x = lo; u.y = hi;
  return __builtin_bit_cast(v4h, u);
}

// ---- Kernel A: per (b, n1): 64 channels x 128-pt forward FFT ---------------
// Wave = 16 channels x 4 q-lanes (lane bits 4..5 = q). Lane q loads rows
// n2 = 32q..32q+31; radix-4 cross combine via shfl_xor(32), shfl_xor(16).
__global__ __launch_bounds__(NTHREADS) void kA(const float* __restrict__ wav,
                                               __half2* __restrict__ ws) {
  const int b = blockIdx.x >> 6, n1 = blockIdx.x & 63;
  const int tid = threadIdx.x, w = tid >> 6, l = tid & 63;
  const int q = l >> 4, cl = l & 15, c = (w << 4) | cl;
  const int SQ = ((q & 1) << 1) | (q >> 1);       // br2(q): {0,2,1,3}
  const bool hiQ = (l & 32) != 0, loQ = (l & 16) != 0;

  const float* wp = wav + ((size_t)b * TT + n1) * CC + c + (size_t)q * (32 * 64 * CC);
  float x[32];
  #pragma unroll
  for (int r = 0; r < 32; ++r) x[r] = wp[(size_t)r * (64 * CC)];

  // cross radix-4 combine + per-lane combine twiddle W128^{-SQ*r}
  const float sqn = (float)SQ * (-1.0f / 128.0f);
  float2 X[32];
  #pragma unroll
  for (int r = 0; r < 32; ++r) {
    const float t = __shfl_xor(x[r], 32, 64);
    const float u = hiQ ? (t - x[r]) : (x[r] + t);
    const float t2 = __shfl_xor(u, 16, 64);
    const float re = hiQ ? (loQ ? t2 : u) : (loQ ? (t2 - u) : (u + t2));
    const float im = hiQ ? (loQ ? u : -t2) : 0.0f;
    if (r == 0) { X[0] = make_float2(re, im); }
    else {
      const float arg = sqn * (float)r;
      const float si = hw_sin(arg), co = hw_cos(arg);
      X[r] = make_float2(re * co - im * si, re * si + im * co);
    }
  }

  // 5 register-resident DIF stages (compile-time twiddles).
  dif_stage<16, 16, false>(X); dif_stage<8, 16, false>(X);
  dif_stage<4, 16, false>(X);  dif_stage<2, 16, false>(X);
  dif_stage<1, 16, false>(X);

  // Output twiddle W8192^{-n1*k2}, k2 = 4r + SQ, position m = br5(r).
  float cd, sd, c0, s0;
  __sincosf(-(TWO_PI / 2048.0f) * (float)n1, &sd, &cd);
  __sincosf(-(TWO_PI / 8192.0f) * (float)(n1 * SQ), &s0, &c0);
  float wc = c0, wsn = s0;
  __half2* wsp = ws + (size_t)b * (128 * 4096) + (size_t)n1 * 64 + c +
                 (size_t)SQ * 4096;
  #pragma unroll
  for (int r = 0; r < 32; ++r) {
    const int m = br5(r);
    const float2 v = cmul(X[m], wc, wsn);
    wsp[(size_t)r * 16384] = __floats2half2_rn(v.x, v.y);
    const float nc = wc * cd - wsn * sd;
    wsn = wc * sd + wsn * cd; wc = nc;
  }
}

// ---- Kernel B (MFMA): per (b, k2): 64-pt fwd DFT, phase replace, inv DFT ---
// Block = 256 thr = 4 waves; wave w owns output rows 16w..16w+15.
// v_mfma_f32_16x16x16_f16 layouts: A[m][k]: m=lane&15, k=4*(lane>>4)+i;
// B[k][n]: k=4*(lane>>4)+i, n=lane&15; D[m][n]: m=4*(lane>>4)+j, n=lane&15.
__global__ __launch_bounds__(NTHREADS) void kB(const __half2* __restrict__ ws,
                                               const float* __restrict__ ph,
                                               const float* __restrict__ mask,
                                               __half2* __restrict__ ws2) {
  const int b = blockIdx.x >> 7, k2 = blockIdx.x & 127;
  const int tid = threadIdx.x, w = tid >> 6, l = tid & 63;
  const int lr = l & 15, lg = l >> 4;

  __shared__ unsigned int Xs[64 * 66];  // [n1][c] half2-dwords, stride 66
  __shared__ unsigned int Ys[64 * 66];  // [k1][c]

  // 1) cooperative stage X global -> LDS (fully coalesced, 2 lanes/bank)
  const unsigned int* gx = (const unsigned int*)(ws + (size_t)blockIdx.x * 4096);
  #pragma unroll
  for (int it = 0; it < 16; ++it) {
    const int idx = it * 256 + tid;
    Xs[(idx >> 6) * 66 + (idx & 63)] = gx[idx];
  }

  // 2) constant DFT A-fragments: F = W64^{-k1*n1} = cos - i sin (symmetric,
  //    so A-layout transpose is irrelevant). Ar=cos, Ai=-sin, mAi=+sin.
  const int mrow = 16 * w + lr;
  v4h Ar[4], Ai[4], mAi[4];
  #pragma unroll
  for (int kt = 0; kt < 4; ++kt) {
    #pragma unroll
    for (int i = 0; i < 4; ++i) {
      const int kk = lg * 4 + i + 16 * kt;
      const float arg = -(float)((mrow * kk) & 63) * (1.0f / 64.0f);
      const float cv = hw_cos(arg), sv = hw_sin(arg);
      Ar[kt][i] = (_Float16)cv;
      Ai[kt][i] = (_Float16)sv;
      mAi[kt][i] = (_Float16)(-sv);
    }
  }
  __syncthreads();

  // 3) per column-tile ct: fwd DFT -> pointwise -> Y to LDS
  const float* php = ph + ((size_t)b * TT + k2) * CC +
                     (size_t)(16 * w + 4 * lg) * 8192;
  #pragma unroll
  for (int ct = 0; ct < 4; ++ct) {
    const int c = 16 * ct + lr;
    v4h Xr[4], Xi[4];
    #pragma unroll
    for (int kt = 0; kt < 4; ++kt) {
      const unsigned int d0 = Xs[(lg * 4 + 0 + 16 * kt) * 66 + c];
      const unsigned int d1 = Xs[(lg * 4 + 1 + 16 * kt) * 66 + c];
      const unsigned int d2 = Xs[(lg * 4 + 2 + 16 * kt) * 66 + c];
      const unsigned int d3 = Xs[(lg * 4 + 3 + 16 * kt) * 66 + c];
      Xr[kt] = mk4h(__builtin_amdgcn_perm(d1, d0, 0x05040100u),
                    __builtin_amdgcn_perm(d3, d2, 0x05040100u));
      Xi[kt] = mk4h(__builtin_amdgcn_perm(d1, d0, 0x07060302u),
                    __builtin_amdgcn_perm(d3, d2, 0x07060302u));
    }
    v4f yR = {0.f, 0.f, 0.f, 0.f}, yI = {0.f, 0.f, 0.f, 0.f};
    #pragma unroll
    for (int kt = 0; kt < 4; ++kt) {
      yR = __builtin_amdgcn_mfma_f32_16x16x16f16(Ar[kt],  Xr[kt], yR, 0, 0, 0);
      yR = __builtin_amdgcn_mfma_f32_16x16x16f16(mAi[kt], Xi[kt], yR, 0, 0, 0);
      yI = __builtin_amdgcn_mfma_f32_16x16x16f16(Ai[kt],  Xr[kt], yI, 0, 0, 0);
      yI = __builtin_amdgcn_mfma_f32_16x16x16f16(Ar[kt],  Xi[kt], yI, 0, 0, 0);
    }
    // pointwise: row j holds k1 = 16w + 4lg + j; full freq k = 128*k1 + k2
    const bool rep = (mask[(b << 6) + c] < 0.5f);
    if (rep) {
      #pragma unroll
      for (int j = 0; j < 4; ++j) {
        const float yr = yR[j], yi = yI[j];
        const float amp = sqrtf(yr * yr + yi * yi);
        const float phi = php[(size_t)j * 8192 + c];  // revolutions
        const float sv = hw_sin(phi), cv = hw_cos(phi);
        yR[j] = amp * cv;
        yI[j] = amp * sv;
      }
    }
    #pragma unroll
    for (int j = 0; j < 4; ++j) {
      Ys[(16 * w + 4 * lg + j) * 66 + c] =
          __builtin_bit_cast(unsigned int, __floats2half2_rn(yR[j], yI[j]));
    }
  }
  __syncthreads();

  // 4) inverse DFT (G = conj(F): Gr=Ar, Gi=mAi) + outer twiddle + store
  float cj[4], sj[4];
  #pragma unroll
  for (int j = 0; j < 4; ++j) {
    const int n1 = 16 * w + 4 * lg + j;
    const float arg = (float)(n1 * k2) * (1.0f / 8192.0f);  // in [0,1)
    cj[j] = hw_cos(arg); sj[j] = hw_sin(arg);
  }
  #pragma unroll
  for (int ct = 0; ct < 4; ++ct) {
    const int c = 16 * ct + lr;
    v4h Yr[4], Yi[4];
    #pragma unroll
    for (int kt = 0; kt < 4; ++kt) {
      const unsigned int d0 = Ys[(lg * 4 + 0 + 16 * kt) * 66 + c];
      const unsigned int d1 = Ys[(lg * 4 + 1 + 16 * kt) * 66 + c];
      const unsigned int d2 = Ys[(lg * 4 + 2 + 16 * kt) * 66 + c];
      const unsigned int d3 = Ys[(lg * 4 + 3 + 16 * kt) * 66 + c];
      Yr[kt] = mk4h(__builtin_amdgcn_perm(d1, d0, 0x05040100u),
                    __builtin_amdgcn_perm(d3, d2, 0x05040100u));
      Yi[kt] = mk4h(__builtin_amdgcn_perm(d1, d0, 0x07060302u),
                    __builtin_amdgcn_perm(d3, d2, 0x07060302u));
    }
    v4f zR = {0.f, 0.f, 0.f, 0.f}, zI = {0.f, 0.f, 0.f, 0.f};
    #pragma unroll
    for (int kt = 0; kt < 4; ++kt) {
      zR = __builtin_amdgcn_mfma_f32_16x16x16f16(Ar[kt],  Yr[kt], zR, 0, 0, 0);
      zR = __builtin_amdgcn_mfma_f32_16x16x16f16(Ai[kt],  Yi[kt], zR, 0, 0, 0);
      zI = __builtin_amdgcn_mfma_f32_16x16x16f16(Ar[kt],  Yi[kt], zI, 0, 0, 0);
      zI = __builtin_amdgcn_mfma_f32_16x16x16f16(mAi[kt], Yr[kt], zI, 0, 0, 0);
    }
    // outer twiddle W8192^{+n1*k2}; store ws2[b][n1][k2][c]
    #pragma unroll
    for (int j = 0; j < 4; ++j) {
      const int n1 = 16 * w + 4 * lg + j;
      const float zr = zR[j] * cj[j] - zI[j] * sj[j];
      const float zi = zR[j] * sj[j] + zI[j] * cj[j];
      ws2[((size_t)(b * 64 + n1) * 128 + k2) * 64 + c] = __floats2half2_rn(zr, zi);
    }
  }
}

// ---- Kernel C: per (b, n1): 64 channels x 128-pt inverse FFT ---------------
__global__ __launch_bounds__(NTHREADS) void kC(const __half2* __restrict__ ws2,
                                               float* __restrict__ out) {
  const int b = blockIdx.x >> 6, n1 = blockIdx.x & 63;
  const int tid = threadIdx.x, w = tid >> 6, l = tid & 63;
  const int q = l >> 4, cl = l & 15, c = (w << 4) | cl;
  const int SQ = ((q & 1) << 1) | (q >> 1);
  const bool hiQ = (l & 32) != 0, loQ = (l & 16) != 0;

  const __half2* rp = ws2 + (size_t)blockIdx.x * 8192 + (size_t)(32 * q) * 64 + c;
  float2 x[32];
  #pragma unroll
  for (int r = 0; r < 32; ++r) x[r] = __half22float2(rp[(size_t)r * 64]);

  // cross radix-4 combine (inverse), per-lane twiddle W128^{+SQ*r}
  const float sqp = (float)SQ * (1.0f / 128.0f);
  float2 X[32];
  #pragma unroll
  for (int r = 0; r < 32; ++r) {
    const float tre = __shfl_xor(x[r].x, 32, 64);
    const float tim = __shfl_xor(x[r].y, 32, 64);
    const float ure = hiQ ? (tre - x[r].x) : (x[r].x + tre);
    const float uim = hiQ ? (tim - x[r].y) : (x[r].y + tim);
    const float t2re = __shfl_xor(ure, 16, 64);
    const float t2im = __shfl_xor(uim, 16, 64);
    const float re = hiQ ? (loQ ? (t2re + uim) : (ure - t2im))
                         : (loQ ? (t2re - ure) : (ure + t2re));
    const float im = hiQ ? (loQ ? (t2im - ure) : (uim + t2re))
                         : (loQ ? (t2im - uim) : (uim + t2im));
    if (r == 0) { X[0] = make_float2(re, im); }
    else {
      const float arg = sqp * (float)r;
      const float si = hw_sin(arg), co = hw_cos(arg);
      X[r] = make_float2(re * co - im * si, re * si + im * co);
    }
  }

  // 5 register-resident inverse DIF stages
  dif_stage<16, 16, true>(X); dif_stage<8, 16, true>(X);
  dif_stage<4, 16, true>(X);  dif_stage<2, 16, true>(X);
  dif_stage<1, 16, true>(X);

  // reg m=br5(r) holds n2 = 4r + SQ: out[b][n1 + 64*n2][c] = Re / 8192
  float* op = out + (size_t)b * (TT * CC) + (size_t)n1 * CC + c + (size_t)SQ * 4096;
  #pragma unroll
  for (int r = 0; r < 32; ++r) {
    const int m = br5(r);
    op[(size_t)r * 16384] = X[m].x * (1.0f / 8192.0f);
  }
}

// ---- Fallback (R1 single-kernel, correct but slow) if ws is too small ----
__global__ __launch_bounds__(NTHREADS) void ft_surrogate_fallback(
    const float* __restrict__ wav, const float* __restrict__ ph,
    const float* __restrict__ mask, float* __restrict__ out) {
  const int bc = blockIdx.x;
  const int c = bc & (CC - 1);
  const int b = bc >> 6;
  const int tid = threadIdx.x;
  const size_t base = (size_t)b * TT * CC + (size_t)c;
  const float m = mask[bc];
  if (!(m < 0.5f)) {
    for (int t = tid; t < TT; t += NTHREADS)
      out[base + (size_t)t * CC] = wav[base + (size_t)t * CC];
    return;
  }
  __shared__ float2 X[TT];
  for (int t = tid; t < TT; t += NTHREADS)
    X[t] = make_float2(wav[base + (size_t)t * CC], 0.0f);
  __syncthreads();
  for (int len = TT, hlf = TT >> 1; len >= 2; len >>= 1, hlf >>= 1) {
    const float ang_scale = -TWO_PI / (float)len;
    for (int it = 0; it < (TT / 2) / NTHREADS; ++it) {
      const int m2 = tid + it * NTHREADS;
      const int j = m2 & (hlf - 1);
      const int i1 = ((m2 & ~(hlf - 1)) << 1) | j;
      const int i2 = i1 + hlf;
      float2 u = X[i1], v = X[i2];
      float ar = u.x + v.x, ai = u.y + v.y;
      float br = u.x - v.x, bi = u.y - v.y;
      float s, cth;
      __sincosf(ang_scale * (float)j, &s, &cth);
      X[i1] = make_float2(ar, ai);
      X[i2] = make_float2(br * cth - bi * s, br * s + bi * cth);
    }
    __syncthreads();
  }
  for (int p = tid; p < TT; p += NTHREADS) {
    const int k = (int)(__brev((unsigned)p) >> (32 - LOG2T));
    float2 v = X[p];
    float amp = sqrtf(v.x * v.x + v.y * v.y);
    float phi = ph[(size_t)b * TT * CC + (size_t)k * CC + (size_t)c];
    float s, cth;
    __sincosf(TWO_PI * phi, &s, &cth);
    X[p] = make_float2(amp * cth, amp * s);
  }
  __syncthreads();
  for (int len = 2, hlf = 1; len <= TT; len <<= 1, hlf <<= 1) {
    const float ang_scale = TWO_PI / (float)len;
    for (int it = 0; it < (TT / 2) / NTHREADS; ++it) {
      const int m2 = tid + it * NTHREADS;
      const int j = m2 & (hlf - 1);
      const int i1 = ((m2 & ~(hlf - 1)) << 1) | j;
      const int i2 = i1 + hlf;
      float s, cth;
      __sincosf(ang_scale * (float)j, &s, &cth);
      float2 u = X[i1], w = X[i2];
      float vr = w.x * cth - w.y * s;
      float vi = w.x * s + w.y * cth;
      X[i1] = make_float2(u.x + vr, u.y + vi);
      X[i2] = make_float2(u.x - vr, u.y - vi);
    }
    __syncthreads();
  }
  const float invN = 1.0f / (float)TT;
  for (int t = tid; t < TT; t += NTHREADS)
    out[base + (size_t)t * CC] = X[t].x * invN;
}

extern "C" void kernel_launch(void* const* d_in, const int* in_sizes, int n_in,
                              void* d_out, int out_size, void* d_ws, size_t ws_size,
                              hipStream_t stream) {
  const float* wav  = (const float*)d_in[0];
  const float* ph   = (const float*)d_in[1];
  const float* mask = (const float*)d_in[2];
  const size_t need = (size_t)BB * TT * CC * sizeof(__half2);  // 128 MB

  if (ws_size >= need) {
    // ws (A->B) aliases d_out; ws2 (B->C) lives in d_ws. Distinct kernels on
    // the same stream order the hazards.
    __half2* ws  = (__half2*)d_out;
    __half2* ws2 = (__half2*)d_ws;
    kA<<<dim3(BB * 64), dim3(NTHREADS), 0, stream>>>(wav, ws);
    kB<<<dim3(BB * 128), dim3(NTHREADS), 0, stream>>>(ws, ph, mask, ws2);
    kC<<<dim3(BB * 64), dim3(NTHREADS), 0, stream>>>(ws2, (float*)d_out);
  } else {
    ft_surrogate_fallback<<<dim3(BB * CC), dim3(NTHREADS), 0, stream>>>(
        wav, ph, mask, (float*)d_out);
  }
}